// Round 12
// baseline (369.688 us; speedup 1.0000x reference)
//
#include <hip/hip_runtime.h>
#include <cstddef>

// InfoNCE loss, B=8192, D=128.
// prep: normalize + bf16(sqrt(S)*e) cast + (label u, conf-sign w) + self-dot
// sim:  triangle-symmetric bf16 MFMA E.E^T, NO LDS / NO BARRIERS, with fin
//       FUSED via last-block-done (threadfence + counter + agent-scope loads).
//       REGISTER LAW, final form (11 rounds): attributes do NOT pin the
//       allocator (wpe(2,2) landed 88 in r11); it voluntarily lands at 60-110.
//       The only spill-free runs had static demand <= ~110. So: 8 waves of
//       16 rows each -> demand ~80 (a 16 + prefetch 32 + sums 16 + chars 8 +
//       temps) -- below anything the heuristic ever chose. No attributes.
// fin:  (fused) per-row loss from (tot, dif), mean over valid rows

#define DDIM 128
#define SQRT_TS 3.7982825f   // sqrt((1/0.1) * log2(e)); applied to both operands

typedef short s8bf __attribute__((ext_vector_type(8)));   // 8 bf16 (4 VGPRs)
typedef float f32x4 __attribute__((ext_vector_type(4)));

__device__ __forceinline__ unsigned short f2bf(float f) {
    unsigned int u = __float_as_uint(f);
    u += 0x7fffu + ((u >> 16) & 1u);
    return (unsigned short)(u >> 16);
}
__device__ __forceinline__ float bf2f(unsigned short h) {
    return __uint_as_float(((unsigned int)h) << 16);
}

// ---------------- prep: one wave per row ----------------
__global__ __launch_bounds__(256) void prep_kernel(
    const float* __restrict__ emb, const int* __restrict__ labels,
    const float* __restrict__ conf,
    short* __restrict__ Eb,    // bf16(sqrt(S) * e) — the ONLY embedding array
    float2* __restrict__ uc,   // (label +-1, conf-sign w)
    float* __restrict__ sd,    // self-dot of scaled bf16 values (log2 domain)
    float* __restrict__ tot, float* __restrict__ dif,
    int* __restrict__ cnt, int B)
{
    if (blockIdx.x == 0 && threadIdx.x == 0) *cnt = 0;

    int wave = threadIdx.x >> 6;
    int lane = threadIdx.x & 63;
    int row  = blockIdx.x * 4 + wave;
    if (row >= B) return;

    float2 x = ((const float2*)(emb + (size_t)row * DDIM))[lane];
    float ss = x.x * x.x + x.y * x.y;
    #pragma unroll
    for (int m = 32; m; m >>= 1) ss += __shfl_xor(ss, m);
    float inv = SQRT_TS / fmaxf(sqrtf(ss), 1e-12f);

    unsigned short eb0 = f2bf(x.x * inv), eb1 = f2bf(x.y * inv);
    *(ushort2*)(Eb + (size_t)row * DDIM + lane * 2) = make_ushort2(eb0, eb1);

    float b0 = bf2f(eb0), b1 = bf2f(eb1);
    float p = b0 * b0 + b1 * b1;
    #pragma unroll
    for (int m = 32; m; m >>= 1) p += __shfl_xor(p, m);

    if (lane == 0) {
        sd[row] = p;
        float l = labels[row] ? 1.0f : -1.0f;
        float c = conf[row];
        float w = (c > 0.0f) ? 1.0f : ((c < 0.0f) ? -1.0f : 0.0f);
        uc[row] = make_float2(l, w);
        tot[row] = 0.0f;
        dif[row] = 0.0f;
    }
}

// ---------------- sim (+fused fin) ----------------
// One upper-triangle 128x128 tile-pair (bi<=bj) per 512-thr block; 8 waves,
// wave w owns rows rowBase..rowBase+15 (ONE 16-row MFMA tile -> ~80 reg demand).
// B-fragments read directly from global (L1/L2-resident), 1-deep prefetch.
// Per element: bias = fma(w_row, w_col*5e29, -5e29); e = exp2(acc + bias);
// row: rtot += e, rdif += u_col*e.  col (off-diag, by symmetry): 2-step shfl
// reduce + direct atomics, fire-and-forget (no barriers in the hot path).
// Last finished block runs the fin reduction with agent-scope atomic loads.
#define MFMA16(A, Bf, C) __builtin_amdgcn_mfma_f32_16x16x32_bf16((A), (Bf), (C), 0, 0, 0)

__global__ __launch_bounds__(512) void sim_kernel(
    const short* __restrict__ Eb, const float2* __restrict__ uc,
    float* __restrict__ tot, float* __restrict__ dif,
    const float* __restrict__ sd, int* __restrict__ cnt,
    float* __restrict__ out, int NT, int B)
{
    const int lane = threadIdx.x & 63;
    const int wave = threadIdx.x >> 6;     // 0..7
    const int l16  = lane & 15;
    const int quad = lane >> 4;

    // triangle decode: bi <= bj, C(i) = i*(M-i)/2, M = 2*NT+1
    const int M = 2 * NT + 1;
    int bid = (int)blockIdx.x;
    int bi = (int)((M - sqrtf((float)(M * M - 8 * bid))) * 0.5f);
    while (bi > 0 && bi * (M - bi) / 2 > bid) --bi;
    while ((bi + 1) * (M - bi - 1) / 2 <= bid) ++bi;
    const int bj = bi + (bid - bi * (M - bi) / 2);
    const bool offdiag = (bi != bj);

    const int rowBase = bi * 128 + wave * 16;   // ONE row-tile per wave
    const int colBase = bj * 128;

    // A fragments (named): A[m=l16][k=quad*8+j]
    const short* pa = Eb + (size_t)(rowBase + l16) * DDIM + quad * 8;
    s8bf a0 = *(const s8bf*)(pa +  0);
    s8bf a1 = *(const s8bf*)(pa + 32);
    s8bf a2 = *(const s8bf*)(pa + 64);
    s8bf a3 = *(const s8bf*)(pa + 96);

    // row characters (4 rows per thread: quad*4 + r); C/D: col=l16, row=quad*4+r
    float2 v0 = uc[rowBase + quad * 4 + 0];
    float2 v1 = uc[rowBase + quad * 4 + 1];
    float2 v2 = uc[rowBase + quad * 4 + 2];
    float2 v3 = uc[rowBase + quad * 4 + 3];
    const float ur0 = v0.x, wr0 = v0.y, ur1 = v1.x, wr1 = v1.y;
    const float ur2 = v2.x, wr2 = v2.y, ur3 = v3.x, wr3 = v3.y;

    float rtot0 = 0, rtot1 = 0, rtot2 = 0, rtot3 = 0;
    float rdif0 = 0, rdif1 = 0, rdif2 = 0, rdif3 = 0;

    #define LDB(w0, w1, w2, w3, ct) do { \
        const short* _p = Eb + (size_t)(colBase + (ct) * 16 + l16) * DDIM + quad * 8; \
        w0 = *(const s8bf*)(_p +  0); \
        w1 = *(const s8bf*)(_p + 32); \
        w2 = *(const s8bf*)(_p + 64); \
        w3 = *(const s8bf*)(_p + 96); \
    } while (0)

    #define CT(w0, w1, w2, w3, ct) do { \
        float2 cj = uc[colBase + (ct) * 16 + l16]; \
        float cby = cj.y * 5e29f; \
        f32x4 acc = {0.f, 0.f, 0.f, 0.f}; \
        acc = MFMA16(a0, w0, acc); \
        acc = MFMA16(a1, w1, acc); \
        acc = MFMA16(a2, w2, acc); \
        acc = MFMA16(a3, w3, acc); \
        float e0 = __builtin_amdgcn_exp2f(acc[0] + fmaf(wr0, cby, -5e29f)); \
        float e1 = __builtin_amdgcn_exp2f(acc[1] + fmaf(wr1, cby, -5e29f)); \
        float e2 = __builtin_amdgcn_exp2f(acc[2] + fmaf(wr2, cby, -5e29f)); \
        float e3 = __builtin_amdgcn_exp2f(acc[3] + fmaf(wr3, cby, -5e29f)); \
        rtot0 += e0; rdif0 = fmaf(cj.x, e0, rdif0); \
        rtot1 += e1; rdif1 = fmaf(cj.x, e1, rdif1); \
        rtot2 += e2; rdif2 = fmaf(cj.x, e2, rdif2); \
        rtot3 += e3; rdif3 = fmaf(cj.x, e3, rdif3); \
        if (offdiag) { \
            float ctA = (e0 + e1) + (e2 + e3); \
            float cdA = fmaf(ur0, e0, fmaf(ur1, e1, fmaf(ur2, e2, ur3 * e3))); \
            ctA += __shfl_xor(ctA, 16); cdA += __shfl_xor(cdA, 16); \
            ctA += __shfl_xor(ctA, 32); cdA += __shfl_xor(cdA, 32); \
            if (quad == 0) { \
                atomicAdd(&tot[colBase + (ct) * 16 + l16], ctA); \
                atomicAdd(&dif[colBase + (ct) * 16 + l16], cdA); \
            } \
        } \
    } while (0)

    // software-pipelined 8 ct-steps, two named prefetch sets (rule #20: no arrays)
    s8bf p0, p1, p2, p3, q0, q1, q2, q3;
    LDB(p0, p1, p2, p3, 0);
    LDB(q0, q1, q2, q3, 1);
    CT(p0, p1, p2, p3, 0); LDB(p0, p1, p2, p3, 2);
    CT(q0, q1, q2, q3, 1); LDB(q0, q1, q2, q3, 3);
    CT(p0, p1, p2, p3, 2); LDB(p0, p1, p2, p3, 4);
    CT(q0, q1, q2, q3, 3); LDB(q0, q1, q2, q3, 5);
    CT(p0, p1, p2, p3, 4); LDB(p0, p1, p2, p3, 6);
    CT(q0, q1, q2, q3, 5); LDB(q0, q1, q2, q3, 7);
    CT(p0, p1, p2, p3, 6);
    CT(q0, q1, q2, q3, 7);

    // ---- row-side flush: reduce over the 16 column-lanes, atomics per row ----
    #define RFLUSH(tv_, dv_, r) do { \
        float tv = (tv_), dv = (dv_); \
        tv += __shfl_xor(tv, 1); dv += __shfl_xor(dv, 1); \
        tv += __shfl_xor(tv, 2); dv += __shfl_xor(dv, 2); \
        tv += __shfl_xor(tv, 4); dv += __shfl_xor(dv, 4); \
        tv += __shfl_xor(tv, 8); dv += __shfl_xor(dv, 8); \
        if (l16 == 0) { \
            int row = rowBase + quad * 4 + (r); \
            atomicAdd(&tot[row], tv); \
            atomicAdd(&dif[row], dv); \
        } \
    } while (0)
    RFLUSH(rtot0, rdif0, 0);
    RFLUSH(rtot1, rdif1, 1);
    RFLUSH(rtot2, rdif2, 2);
    RFLUSH(rtot3, rdif3, 3);

    // ---- fused fin: last finished block reduces ----
    __shared__ int amLast;
    __shared__ float ssum[8], scnt[8];
    __threadfence();   // all our atomics visible before the counter bump
    if (threadIdx.x == 0) {
        int old = atomicAdd(cnt, 1);
        amLast = (old == (int)gridDim.x - 1);
    }
    __syncthreads();
    if (!amLast) return;

    __threadfence();   // acquire side: see all other blocks' atomics
    float sum = 0.0f, cn = 0.0f;
    for (int i = threadIdx.x; i < B; i += 512) {
        float u = uc[i].x;
        float P = __hip_atomic_load(&tot[i], __ATOMIC_RELAXED, __HIP_MEMORY_SCOPE_AGENT);
        float D = __hip_atomic_load(&dif[i], __ATOMIC_RELAXED, __HIP_MEMORY_SCOPE_AGENT);
        float Q = u * D;
        // pos (excl. diag) = (P+Q)/2 - exp2(sd); invalid rows have P=Q=0 -> skipped
        float pos = 0.5f * (P + Q) - __builtin_amdgcn_exp2f(sd[i]);
        float neg = 0.5f * (P - Q);
        if (pos > 0.0f && neg > 0.0f) {
            sum += logf((pos + neg + 1e-8f) / pos);
            cn  += 1.0f;
        }
    }
    #pragma unroll
    for (int m = 32; m; m >>= 1) {
        sum += __shfl_xor(sum, m);
        cn  += __shfl_xor(cn, m);
    }
    if (lane == 0) { ssum[wave] = sum; scnt[wave] = cn; }
    __syncthreads();
    if (threadIdx.x == 0) {
        float S = 0.0f, C = 0.0f;
        #pragma unroll
        for (int w = 0; w < 8; ++w) { S += ssum[w]; C += scnt[w]; }
        out[0] = (C > 0.0f) ? S / fmaxf(C, 1.0f) : 0.0f;
    }
}

extern "C" void kernel_launch(void* const* d_in, const int* in_sizes, int n_in,
                              void* d_out, int out_size, void* d_ws, size_t ws_size,
                              hipStream_t stream) {
    const float* emb    = (const float*)d_in[0];
    const int*   labels = (const int*)d_in[1];
    const float* conf   = (const float*)d_in[2];
    float* out = (float*)d_out;
    int B = in_sizes[1];   // 8192

    char* ws = (char*)d_ws;
    size_t off = 0;
    short*  Eb  = (short*)(ws + off);  off += (size_t)B * DDIM * 2;
    float2* ucp = (float2*)(ws + off); off += (size_t)B * 8;
    float*  sd  = (float*)(ws + off);  off += (size_t)B * 4;
    float*  tot = (float*)(ws + off);  off += (size_t)B * 4;
    float*  dif = (float*)(ws + off);  off += (size_t)B * 4;
    int*    cnt = (int*)(ws + off);    off += 256;

    prep_kernel<<<B / 4, 256, 0, stream>>>(emb, labels, conf, Eb, ucp, sd, tot, dif, cnt, B);

    int NT = B / 128;                    // 64 tiles per side
    int nblk = NT * (NT + 1) / 2;        // 2080 upper-triangle tile-pairs
    sim_kernel<<<nblk, 512, 0, stream>>>(Eb, ucp, tot, dif, sd, cnt, out, NT, B);
}

// Round 13
// 123.215 us; speedup vs baseline: 3.0004x; 3.0004x over previous
//
#include <hip/hip_runtime.h>
#include <cstddef>

// InfoNCE loss, B=8192, D=128.
// prep: normalize + bf16(sqrt(S)*e) cast + (label u, conf-sign w) + self-dot
// sim:  r9 structure (best measured: 97.5us total) + two deltas:
//       (1) col-side atomics issued AFTER the phase barrier (held in regs),
//           so the barrier's vmcnt(0) drain no longer eats ~500cyc of L2
//           atomic RTT per phase (r7 diagnosis, finally applied);
//       (2) fin fused via last-block-done counter (r12-verified pattern).
//       Triangle-symmetric bf16 MFMA E.E^T, 2 tile-pairs per block, dbuf
//       64-col half-tiles via swizzled gload_lds, wpe(2,4) as r9.
// fin:  (fused) per-row loss from (tot, dif), mean over valid rows

#define DDIM 128
#define SQRT_TS 3.7982825f   // sqrt((1/0.1) * log2(e)); applied to both operands
#define CHUNK 2              // 128x128 tile-pairs per block; 2080/2 = 1040 blocks

typedef short s8bf __attribute__((ext_vector_type(8)));   // 8 bf16 (4 VGPRs)
typedef float f32x4 __attribute__((ext_vector_type(4)));

typedef __attribute__((address_space(1))) void gas_void;
typedef __attribute__((address_space(3))) void las_void;

__device__ __forceinline__ void gload_lds16(const void* g, void* l) {
    __builtin_amdgcn_global_load_lds((gas_void*)g, (las_void*)l, 16, 0, 0);
}

__device__ __forceinline__ unsigned short f2bf(float f) {
    unsigned int u = __float_as_uint(f);
    u += 0x7fffu + ((u >> 16) & 1u);
    return (unsigned short)(u >> 16);
}
__device__ __forceinline__ float bf2f(unsigned short h) {
    return __uint_as_float(((unsigned int)h) << 16);
}

// ---------------- prep: one wave per row ----------------
__global__ __launch_bounds__(256) void prep_kernel(
    const float* __restrict__ emb, const int* __restrict__ labels,
    const float* __restrict__ conf,
    short* __restrict__ Eb,    // bf16(sqrt(S) * e) — the ONLY embedding array
    float2* __restrict__ uc,   // (label +-1, conf-sign w)
    float* __restrict__ sd,    // self-dot of scaled bf16 values (log2 domain)
    float* __restrict__ tot, float* __restrict__ dif,
    int* __restrict__ cnt, int B)
{
    if (blockIdx.x == 0 && threadIdx.x == 0) *cnt = 0;

    int wave = threadIdx.x >> 6;
    int lane = threadIdx.x & 63;
    int row  = blockIdx.x * 4 + wave;
    if (row >= B) return;

    float2 x = ((const float2*)(emb + (size_t)row * DDIM))[lane];
    float ss = x.x * x.x + x.y * x.y;
    #pragma unroll
    for (int m = 32; m; m >>= 1) ss += __shfl_xor(ss, m);
    float inv = SQRT_TS / fmaxf(sqrtf(ss), 1e-12f);

    unsigned short eb0 = f2bf(x.x * inv), eb1 = f2bf(x.y * inv);
    *(ushort2*)(Eb + (size_t)row * DDIM + lane * 2) = make_ushort2(eb0, eb1);

    float b0 = bf2f(eb0), b1 = bf2f(eb1);
    float p = b0 * b0 + b1 * b1;
    #pragma unroll
    for (int m = 32; m; m >>= 1) p += __shfl_xor(p, m);

    if (lane == 0) {
        sd[row] = p;
        float l = labels[row] ? 1.0f : -1.0f;
        float c = conf[row];
        float w = (c > 0.0f) ? 1.0f : ((c < 0.0f) ? -1.0f : 0.0f);
        uc[row] = make_float2(l, w);
        tot[row] = 0.0f;
        dif[row] = 0.0f;
    }
}

// ---------------- sim (+fused fin) ----------------
// Upper-triangle 128x128 tile-pairs (bi<=bj), lexicographic, CHUNK per block.
// 64-col half-tiles double-buffered (16 KB each) via swizzled gload_lds
// (LDS[L] = G[L ^ ((L>>8&7)<<4)]; reads apply same XOR; r5-r9 verified).
// Per element: bias = fma(w_row, w_col*5e29, -5e29); e = exp2(acc + bias);
// row: rtot += e, rdif += u_col*e (regs, flushed per panel).
// col (off-diag only, by symmetry): reduced over quads before the barrier
// (shfl = lgkm, not vmcnt), atomics ISSUED AFTER the barrier -> retire under
// the next compute phase instead of stalling the barrier drain.
#define MFMA16(A, Bf, C) __builtin_amdgcn_mfma_f32_16x16x32_bf16((A), (Bf), (C), 0, 0, 0)

__device__ __forceinline__ void stage_half(const short* __restrict__ Eb, int colBase,
                                           short* buf, int wave, int lane) {
    // 64 cols x 256 B = 16 KB; 256 thr x 4 x 16 B
    const char* gb = (const char*)Eb + (size_t)colBase * 256;
    #pragma unroll
    for (int i = 0; i < 4; ++i) {
        int L  = i * 4096 + wave * 1024 + lane * 16;
        int Ls = L ^ (((L >> 8) & 7) << 4);   // inverse-swizzled source
        gload_lds16(gb + Ls, (char*)buf + L);
    }
}

__global__ __launch_bounds__(256) __attribute__((amdgpu_waves_per_eu(2, 4)))
void sim_kernel(
    const short* __restrict__ Eb, const float2* __restrict__ uc,
    float* __restrict__ tot, float* __restrict__ dif,
    const float* __restrict__ sd, int* __restrict__ cnt,
    float* __restrict__ out, int NT, int B)
{
    __shared__ short tile[2][64 * 128];   // 2 x 16 KB halves, swizzled, linear

    const int lane = threadIdx.x & 63;
    const int wave = threadIdx.x >> 6;
    const int l16  = lane & 15;
    const int quad = lane >> 4;
    const int swz  = (l16 & 7) << 4;

    // triangle decode of chunk start: C(i) = i*(M-i)/2, M = 2*NT+1
    const int M = 2 * NT + 1;
    int bid = (int)blockIdx.x * CHUNK;
    int bi = (int)((M - sqrtf((float)(M * M - 8 * bid))) * 0.5f);
    while (bi > 0 && bi * (M - bi) / 2 > bid) --bi;
    while ((bi + 1) * (M - bi - 1) / 2 <= bid) ++bi;
    int bj = bi + (bid - bi * (M - bi) / 2);

    s8bf a[2][4];
    float ur[2][4], wr[2][4], rtot[2][4], rdif[2][4];

    #define LOAD_ROWPANEL(bi_) do { \
        int rb = (bi_) * 128 + wave * 32; \
        _Pragma("unroll") for (int t = 0; t < 2; ++t) \
            _Pragma("unroll") for (int k2 = 0; k2 < 4; ++k2) \
                a[t][k2] = *(const s8bf*)(Eb + (size_t)(rb + t * 16 + l16) * DDIM + k2 * 32 + quad * 8); \
        _Pragma("unroll") for (int t = 0; t < 2; ++t) \
            _Pragma("unroll") for (int r = 0; r < 4; ++r) { \
                float2 v = uc[rb + t * 16 + quad * 4 + r]; \
                ur[t][r] = v.x; wr[t][r] = v.y; \
                rtot[t][r] = 0.0f; rdif[t][r] = 0.0f; } \
    } while (0)

    #define FLUSH_ROWS(bi_) do { \
        _Pragma("unroll") for (int t = 0; t < 2; ++t) \
            _Pragma("unroll") for (int r = 0; r < 4; ++r) { \
                float tv = rtot[t][r], dv = rdif[t][r]; \
                tv += __shfl_xor(tv, 1); dv += __shfl_xor(dv, 1); \
                tv += __shfl_xor(tv, 2); dv += __shfl_xor(dv, 2); \
                tv += __shfl_xor(tv, 4); dv += __shfl_xor(dv, 4); \
                tv += __shfl_xor(tv, 8); dv += __shfl_xor(dv, 8); \
                if (l16 == 0) { \
                    int row = (bi_) * 128 + wave * 32 + t * 16 + quad * 4 + r; \
                    atomicAdd(&tot[row], tv); \
                    atomicAdd(&dif[row], dv); } } \
    } while (0)

    // one ct-step: 16 cols from the current half-buffer; cj direct from L1/L2
    #define CT(ct, ctAcc, cdAcc, bufp, scol) do { \
        const char* tb = (const char*)&tile[bufp][0] + ((ct) * 16 + l16) * 256; \
        s8bf b0 = *(const s8bf*)(tb + ((  0 + quad * 16) ^ swz)); \
        s8bf b1 = *(const s8bf*)(tb + (( 64 + quad * 16) ^ swz)); \
        s8bf b2 = *(const s8bf*)(tb + ((128 + quad * 16) ^ swz)); \
        s8bf b3 = *(const s8bf*)(tb + ((192 + quad * 16) ^ swz)); \
        float2 cj = uc[(scol) + (ct) * 16 + l16]; \
        float cby = cj.y * 5e29f; \
        f32x4 acc0 = {0.f,0.f,0.f,0.f}, acc1 = {0.f,0.f,0.f,0.f}; \
        acc0 = MFMA16(a[0][0], b0, acc0); \
        acc0 = MFMA16(a[0][1], b1, acc0); \
        acc0 = MFMA16(a[0][2], b2, acc0); \
        acc0 = MFMA16(a[0][3], b3, acc0); \
        acc1 = MFMA16(a[1][0], b0, acc1); \
        acc1 = MFMA16(a[1][1], b1, acc1); \
        acc1 = MFMA16(a[1][2], b2, acc1); \
        acc1 = MFMA16(a[1][3], b3, acc1); \
        _Pragma("unroll") for (int r = 0; r < 4; ++r) { \
            float bias = fmaf(wr[0][r], cby, -5e29f); \
            float e = __builtin_amdgcn_exp2f(acc0[r] + bias); \
            rtot[0][r] += e; rdif[0][r] = fmaf(cj.x, e, rdif[0][r]); \
            ctAcc += e;      cdAcc   = fmaf(ur[0][r], e, cdAcc); } \
        _Pragma("unroll") for (int r = 0; r < 4; ++r) { \
            float bias = fmaf(wr[1][r], cby, -5e29f); \
            float e = __builtin_amdgcn_exp2f(acc1[r] + bias); \
            rtot[1][r] += e; rdif[1][r] = fmaf(cj.x, e, rdif[1][r]); \
            ctAcc += e;      cdAcc   = fmaf(ur[1][r], e, cdAcc); } \
    } while (0)

    // prologue: stage half 0 of tile 0; row panel loads overlap the DMA
    stage_half(Eb, bj * 128, &tile[0][0], wave, lane);
    LOAD_ROWPANEL(bi);
    int cur_bi = bi;
    __syncthreads();   // drains DMA

    int cbi = bi, cbj = bj;            // current tile
    int nbi = bi, nbj = bj + 1;        // next tile
    if (nbj == NT) { ++nbi; nbj = nbi; }

    // pending col-side partials (issued one phase late, after the barrier)
    bool  pend = false;
    int   pendCol = 0;
    float pc0 = 0, pc1 = 0, pc2 = 0, pc3 = 0;
    float pd0 = 0, pd1 = 0, pd2 = 0, pd3 = 0;

    #pragma unroll 1
    for (int p = 0; p < 2 * CHUNK; ++p) {
        const int h = p & 1;           // half within current tile
        const int bufp = p & 1;

        // stage next half (h==0 -> second half of cur tile; h==1 -> first of next)
        if (p + 1 < 2 * CHUNK) {
            int scoln = (h ? nbj : cbj) * 128 + (h ? 0 : 64);
            stage_half(Eb, scoln, &tile[bufp ^ 1][0], wave, lane);
        }
        __builtin_amdgcn_sched_barrier(0);

        // issue last phase's col atomics NOW: they retire under this compute
        if (pend) {
            if (quad == 0) {
                atomicAdd(&tot[pendCol +  0], pc0); atomicAdd(&dif[pendCol +  0], pd0);
                atomicAdd(&tot[pendCol + 16], pc1); atomicAdd(&dif[pendCol + 16], pd1);
                atomicAdd(&tot[pendCol + 32], pc2); atomicAdd(&dif[pendCol + 32], pd2);
                atomicAdd(&tot[pendCol + 48], pc3); atomicAdd(&dif[pendCol + 48], pd3);
            }
            pend = false;
        }

        if (h == 0 && cbi != cur_bi) {   // rare: row panel changed
            FLUSH_ROWS(cur_bi);
            LOAD_ROWPANEL(cbi);
            cur_bi = cbi;
        }

        const int scol = cbj * 128 + h * 64;
        float ctA0 = 0, cdA0 = 0, ctA1 = 0, cdA1 = 0;
        float ctA2 = 0, cdA2 = 0, ctA3 = 0, cdA3 = 0;
        CT(0, ctA0, cdA0, bufp, scol);
        CT(1, ctA1, cdA1, bufp, scol);
        CT(2, ctA2, cdA2, bufp, scol);
        CT(3, ctA3, cdA3, bufp, scol);

        // quad-reduce before the barrier (shfl = lgkm pipe, not in vmcnt drain)
        if (cbi != cbj) {
            ctA0 += __shfl_xor(ctA0, 16); cdA0 += __shfl_xor(cdA0, 16);
            ctA1 += __shfl_xor(ctA1, 16); cdA1 += __shfl_xor(cdA1, 16);
            ctA2 += __shfl_xor(ctA2, 16); cdA2 += __shfl_xor(cdA2, 16);
            ctA3 += __shfl_xor(ctA3, 16); cdA3 += __shfl_xor(cdA3, 16);
            ctA0 += __shfl_xor(ctA0, 32); cdA0 += __shfl_xor(cdA0, 32);
            ctA1 += __shfl_xor(ctA1, 32); cdA1 += __shfl_xor(cdA1, 32);
            ctA2 += __shfl_xor(ctA2, 32); cdA2 += __shfl_xor(cdA2, 32);
            ctA3 += __shfl_xor(ctA3, 32); cdA3 += __shfl_xor(cdA3, 32);
            pend = true; pendCol = scol + l16;
            pc0 = ctA0; pc1 = ctA1; pc2 = ctA2; pc3 = ctA3;
            pd0 = cdA0; pd1 = cdA1; pd2 = cdA2; pd3 = cdA3;
        }
        __syncthreads();   // closes read window on tile[bufp]; drains next DMA

        if (h == 1) {      // advance to next tile
            cbi = nbi; cbj = nbj;
            if (++nbj == NT) { ++nbi; nbj = nbi; }
        }
    }
    // final pending col atomics + row flush
    if (pend && quad == 0) {
        atomicAdd(&tot[pendCol +  0], pc0); atomicAdd(&dif[pendCol +  0], pd0);
        atomicAdd(&tot[pendCol + 16], pc1); atomicAdd(&dif[pendCol + 16], pd1);
        atomicAdd(&tot[pendCol + 32], pc2); atomicAdd(&dif[pendCol + 32], pd2);
        atomicAdd(&tot[pendCol + 48], pc3); atomicAdd(&dif[pendCol + 48], pd3);
    }
    FLUSH_ROWS(cur_bi);

    // ---- fused fin: last finished block reduces (r12-verified pattern) ----
    __shared__ int amLast;
    __shared__ float ssum[4], scnt4[4];
    __syncthreads();   // vmcnt(0) drain: ALL this block's atomics complete
    if (threadIdx.x == 0) {
        __threadfence();
        int old = atomicAdd(cnt, 1);
        amLast = (old == (int)gridDim.x - 1);
    }
    __syncthreads();
    if (!amLast) return;

    __threadfence();   // acquire: see all other blocks' atomics
    float sum = 0.0f, cn = 0.0f;
    for (int i = threadIdx.x; i < B; i += 256) {
        float u = uc[i].x;
        float P = __hip_atomic_load(&tot[i], __ATOMIC_RELAXED, __HIP_MEMORY_SCOPE_AGENT);
        float D = __hip_atomic_load(&dif[i], __ATOMIC_RELAXED, __HIP_MEMORY_SCOPE_AGENT);
        float Q = u * D;
        // pos (excl. diag) = (P+Q)/2 - exp2(sd); invalid rows have P=Q=0 -> skipped
        float pos = 0.5f * (P + Q) - __builtin_amdgcn_exp2f(sd[i]);
        float neg = 0.5f * (P - Q);
        if (pos > 0.0f && neg > 0.0f) {
            sum += logf((pos + neg + 1e-8f) / pos);
            cn  += 1.0f;
        }
    }
    #pragma unroll
    for (int m = 32; m; m >>= 1) {
        sum += __shfl_xor(sum, m);
        cn  += __shfl_xor(cn, m);
    }
    if (lane == 0) { ssum[wave] = sum; scnt4[wave] = cn; }
    __syncthreads();
    if (threadIdx.x == 0) {
        float S = 0.0f, C = 0.0f;
        #pragma unroll
        for (int w = 0; w < 4; ++w) { S += ssum[w]; C += scnt4[w]; }
        out[0] = (C > 0.0f) ? S / fmaxf(C, 1.0f) : 0.0f;
    }
}

extern "C" void kernel_launch(void* const* d_in, const int* in_sizes, int n_in,
                              void* d_out, int out_size, void* d_ws, size_t ws_size,
                              hipStream_t stream) {
    const float* emb    = (const float*)d_in[0];
    const int*   labels = (const int*)d_in[1];
    const float* conf   = (const float*)d_in[2];
    float* out = (float*)d_out;
    int B = in_sizes[1];   // 8192

    char* ws = (char*)d_ws;
    size_t off = 0;
    short*  Eb  = (short*)(ws + off);  off += (size_t)B * DDIM * 2;
    float2* ucp = (float2*)(ws + off); off += (size_t)B * 8;
    float*  sd  = (float*)(ws + off);  off += (size_t)B * 4;
    float*  tot = (float*)(ws + off);  off += (size_t)B * 4;
    float*  dif = (float*)(ws + off);  off += (size_t)B * 4;
    int*    cnt = (int*)(ws + off);    off += 256;

    prep_kernel<<<B / 4, 256, 0, stream>>>(emb, labels, conf, Eb, ucp, sd, tot, dif, cnt, B);

    int NT = B / 128;                      // 64 tiles per side
    int nblk = NT * (NT + 1) / 2 / CHUNK;  // 2080/2 = 1040 blocks -> ~4/CU
    sim_kernel<<<nblk, 256, 0, stream>>>(Eb, ucp, tot, dif, sd, cnt, out, NT, B);
}

// Round 14
// 97.522 us; speedup vs baseline: 3.7908x; 1.2635x over previous
//
#include <hip/hip_runtime.h>
#include <cstddef>

// InfoNCE loss, B=8192, D=128.
// prep: normalize + bf16(sqrt(S)*e) cast + (label u, conf-sign w) + self-dot
// sim:  triangle-symmetric bf16 MFMA E.E^T. 2 tile-pairs per block, staged as
//       double-buffered 64-col HALF-tiles (2x16 KB LDS -> 4 blocks/CU).
//       This is the r9 configuration EXACTLY (best measured: 97.5us; sim ~37us,
//       no spill). Rounds 10-13 each perturbed it (no-LDS, 8-wave, deferred
//       atomics, fused fin) and each regressed via the same mechanism: the
//       register allocator's erratic target (48-128 observed) turns any added
//       live state into a scratch-spill cliff (~900cyc RTTs in the hot loop).
//       r9's live-state budget is the empirically proven safe point. Do not
//       add registers to this kernel.
// fin:  per-row loss from (tot, dif), mean over valid rows

#define DDIM 128
#define SQRT_TS 3.7982825f   // sqrt((1/0.1) * log2(e)); applied to both operands
#define CHUNK 2              // 128x128 tile-pairs per block; 2080/2 = 1040 blocks

typedef short s8bf __attribute__((ext_vector_type(8)));   // 8 bf16 (4 VGPRs)
typedef float f32x4 __attribute__((ext_vector_type(4)));

typedef __attribute__((address_space(1))) void gas_void;
typedef __attribute__((address_space(3))) void las_void;

__device__ __forceinline__ void gload_lds16(const void* g, void* l) {
    __builtin_amdgcn_global_load_lds((gas_void*)g, (las_void*)l, 16, 0, 0);
}

__device__ __forceinline__ unsigned short f2bf(float f) {
    unsigned int u = __float_as_uint(f);
    u += 0x7fffu + ((u >> 16) & 1u);
    return (unsigned short)(u >> 16);
}
__device__ __forceinline__ float bf2f(unsigned short h) {
    return __uint_as_float(((unsigned int)h) << 16);
}

// ---------------- prep: one wave per row ----------------
__global__ __launch_bounds__(256) void prep_kernel(
    const float* __restrict__ emb, const int* __restrict__ labels,
    const float* __restrict__ conf,
    short* __restrict__ Eb,    // bf16(sqrt(S) * e) — the ONLY embedding array
    float2* __restrict__ uc,   // (label +-1, conf-sign w)
    float* __restrict__ sd,    // self-dot of scaled bf16 values (log2 domain)
    float* __restrict__ tot, float* __restrict__ dif, int B)
{
    int wave = threadIdx.x >> 6;
    int lane = threadIdx.x & 63;
    int row  = blockIdx.x * 4 + wave;
    if (row >= B) return;

    float2 x = ((const float2*)(emb + (size_t)row * DDIM))[lane];
    float ss = x.x * x.x + x.y * x.y;
    #pragma unroll
    for (int m = 32; m; m >>= 1) ss += __shfl_xor(ss, m);
    float inv = SQRT_TS / fmaxf(sqrtf(ss), 1e-12f);

    unsigned short eb0 = f2bf(x.x * inv), eb1 = f2bf(x.y * inv);
    *(ushort2*)(Eb + (size_t)row * DDIM + lane * 2) = make_ushort2(eb0, eb1);

    float b0 = bf2f(eb0), b1 = bf2f(eb1);
    float p = b0 * b0 + b1 * b1;
    #pragma unroll
    for (int m = 32; m; m >>= 1) p += __shfl_xor(p, m);

    if (lane == 0) {
        sd[row] = p;
        float l = labels[row] ? 1.0f : -1.0f;
        float c = conf[row];
        float w = (c > 0.0f) ? 1.0f : ((c < 0.0f) ? -1.0f : 0.0f);
        uc[row] = make_float2(l, w);
        tot[row] = 0.0f;
        dif[row] = 0.0f;
    }
}

// ---------------- sim ----------------
// Upper-triangle 128x128 tile-pairs (bi<=bj), lexicographic, CHUNK per block.
// Staging granularity: 64-col half-tiles, double-buffered (16 KB each) via
// swizzled gload_lds (LDS[L] = G[L ^ ((L>>8&7)<<4)]; reads apply same XOR).
// Per element: bias = fma(w_row, w_col*5e29, -5e29); e = exp2(acc + bias);
// row: rtot += e, rdif += u_col*e (regs, flushed per panel).
// col (off-diag tiles only, by symmetry): per-ct reg accumulators, reduced over
// quads at HALF end (4 independent shfl chains), atomicAdd from quad-0 lanes.
#define MFMA16(A, Bf, C) __builtin_amdgcn_mfma_f32_16x16x32_bf16((A), (Bf), (C), 0, 0, 0)

__device__ __forceinline__ void stage_half(const short* __restrict__ Eb, int colBase,
                                           short* buf, int wave, int lane) {
    // 64 cols x 256 B = 16 KB; 256 thr x 4 x 16 B
    const char* gb = (const char*)Eb + (size_t)colBase * 256;
    #pragma unroll
    for (int i = 0; i < 4; ++i) {
        int L  = i * 4096 + wave * 1024 + lane * 16;
        int Ls = L ^ (((L >> 8) & 7) << 4);   // inverse-swizzled source
        gload_lds16(gb + Ls, (char*)buf + L);
    }
}

__global__ __launch_bounds__(256) __attribute__((amdgpu_waves_per_eu(2, 4)))
void sim_kernel(
    const short* __restrict__ Eb, const float2* __restrict__ uc,
    float* __restrict__ tot, float* __restrict__ dif, int NT)
{
    __shared__ short tile[2][64 * 128];   // 2 x 16 KB halves, swizzled, linear
    __shared__ float2 ucc[2][64];         // col (u, w) per half

    const int lane = threadIdx.x & 63;
    const int wave = threadIdx.x >> 6;
    const int l16  = lane & 15;
    const int quad = lane >> 4;
    const int swz  = (l16 & 7) << 4;

    // triangle decode of chunk start: C(i) = i*(M-i)/2, M = 2*NT+1
    const int M = 2 * NT + 1;
    int bid = (int)blockIdx.x * CHUNK;
    int bi = (int)((M - sqrtf((float)(M * M - 8 * bid))) * 0.5f);
    while (bi > 0 && bi * (M - bi) / 2 > bid) --bi;
    while ((bi + 1) * (M - bi - 1) / 2 <= bid) ++bi;
    int bj = bi + (bid - bi * (M - bi) / 2);

    s8bf a[2][4];
    float ur[2][4], wr[2][4], rtot[2][4], rdif[2][4];

    #define LOAD_ROWPANEL(bi_) do { \
        int rb = (bi_) * 128 + wave * 32; \
        _Pragma("unroll") for (int t = 0; t < 2; ++t) \
            _Pragma("unroll") for (int k2 = 0; k2 < 4; ++k2) \
                a[t][k2] = *(const s8bf*)(Eb + (size_t)(rb + t * 16 + l16) * DDIM + k2 * 32 + quad * 8); \
        _Pragma("unroll") for (int t = 0; t < 2; ++t) \
            _Pragma("unroll") for (int r = 0; r < 4; ++r) { \
                float2 v = uc[rb + t * 16 + quad * 4 + r]; \
                ur[t][r] = v.x; wr[t][r] = v.y; \
                rtot[t][r] = 0.0f; rdif[t][r] = 0.0f; } \
    } while (0)

    #define FLUSH_ROWS(bi_) do { \
        _Pragma("unroll") for (int t = 0; t < 2; ++t) \
            _Pragma("unroll") for (int r = 0; r < 4; ++r) { \
                float tv = rtot[t][r], dv = rdif[t][r]; \
                tv += __shfl_xor(tv, 1); dv += __shfl_xor(dv, 1); \
                tv += __shfl_xor(tv, 2); dv += __shfl_xor(dv, 2); \
                tv += __shfl_xor(tv, 4); dv += __shfl_xor(dv, 4); \
                tv += __shfl_xor(tv, 8); dv += __shfl_xor(dv, 8); \
                if (l16 == 0) { \
                    int row = (bi_) * 128 + wave * 32 + t * 16 + quad * 4 + r; \
                    atomicAdd(&tot[row], tv); \
                    atomicAdd(&dif[row], dv); } } \
    } while (0)

    // one ct-step: 16 cols from the current half-buffer
    #define CT(ct, ctAcc, cdAcc, bufp) do { \
        const char* tb = (const char*)&tile[bufp][0] + ((ct) * 16 + l16) * 256; \
        s8bf b0 = *(const s8bf*)(tb + ((  0 + quad * 16) ^ swz)); \
        s8bf b1 = *(const s8bf*)(tb + (( 64 + quad * 16) ^ swz)); \
        s8bf b2 = *(const s8bf*)(tb + ((128 + quad * 16) ^ swz)); \
        s8bf b3 = *(const s8bf*)(tb + ((192 + quad * 16) ^ swz)); \
        float2 cj = ucc[bufp][(ct) * 16 + l16]; \
        float cby = cj.y * 5e29f; \
        f32x4 acc0 = {0.f,0.f,0.f,0.f}, acc1 = {0.f,0.f,0.f,0.f}; \
        acc0 = MFMA16(a[0][0], b0, acc0); \
        acc0 = MFMA16(a[0][1], b1, acc0); \
        acc0 = MFMA16(a[0][2], b2, acc0); \
        acc0 = MFMA16(a[0][3], b3, acc0); \
        acc1 = MFMA16(a[1][0], b0, acc1); \
        acc1 = MFMA16(a[1][1], b1, acc1); \
        acc1 = MFMA16(a[1][2], b2, acc1); \
        acc1 = MFMA16(a[1][3], b3, acc1); \
        _Pragma("unroll") for (int r = 0; r < 4; ++r) { \
            float bias = fmaf(wr[0][r], cby, -5e29f); \
            float e = __builtin_amdgcn_exp2f(acc0[r] + bias); \
            rtot[0][r] += e; rdif[0][r] = fmaf(cj.x, e, rdif[0][r]); \
            ctAcc += e;      cdAcc   = fmaf(ur[0][r], e, cdAcc); } \
        _Pragma("unroll") for (int r = 0; r < 4; ++r) { \
            float bias = fmaf(wr[1][r], cby, -5e29f); \
            float e = __builtin_amdgcn_exp2f(acc1[r] + bias); \
            rtot[1][r] += e; rdif[1][r] = fmaf(cj.x, e, rdif[1][r]); \
            ctAcc += e;      cdAcc   = fmaf(ur[1][r], e, cdAcc); } \
    } while (0)

    // prologue: stage half 0 of tile 0; row panel loads overlap the DMA
    stage_half(Eb, bj * 128, &tile[0][0], wave, lane);
    if (threadIdx.x < 64) ucc[0][threadIdx.x] = uc[bj * 128 + threadIdx.x];
    LOAD_ROWPANEL(bi);
    int cur_bi = bi;
    __syncthreads();   // drains DMA; ucc visible

    int cbi = bi, cbj = bj;            // current tile
    int nbi = bi, nbj = bj + 1;        // next tile
    if (nbj == NT) { ++nbi; nbj = nbi; }

    #pragma unroll 1
    for (int p = 0; p < 2 * CHUNK; ++p) {
        const int h = p & 1;           // half within current tile
        const int bufp = p & 1;

        // stage next half (h==0 -> second half of cur tile; h==1 -> first of next)
        if (p + 1 < 2 * CHUNK) {
            int scol = (h ? nbj : cbj) * 128 + (h ? 0 : 64);
            stage_half(Eb, scol, &tile[bufp ^ 1][0], wave, lane);
            if (threadIdx.x < 64) ucc[bufp ^ 1][threadIdx.x] = uc[scol + threadIdx.x];
        }
        __builtin_amdgcn_sched_barrier(0);

        if (h == 0 && cbi != cur_bi) {   // rare: row panel changed
            FLUSH_ROWS(cur_bi);
            LOAD_ROWPANEL(cbi);
            cur_bi = cbi;
        }

        float ctA0 = 0, cdA0 = 0, ctA1 = 0, cdA1 = 0;
        float ctA2 = 0, cdA2 = 0, ctA3 = 0, cdA3 = 0;
        CT(0, ctA0, cdA0, bufp);
        CT(1, ctA1, cdA1, bufp);
        CT(2, ctA2, cdA2, bufp);
        CT(3, ctA3, cdA3, bufp);

        // batched col reduce: 4 independent 2-step chains (latencies overlap)
        if (cbi != cbj) {
            ctA0 += __shfl_xor(ctA0, 16); cdA0 += __shfl_xor(cdA0, 16);
            ctA1 += __shfl_xor(ctA1, 16); cdA1 += __shfl_xor(cdA1, 16);
            ctA2 += __shfl_xor(ctA2, 16); cdA2 += __shfl_xor(cdA2, 16);
            ctA3 += __shfl_xor(ctA3, 16); cdA3 += __shfl_xor(cdA3, 16);
            ctA0 += __shfl_xor(ctA0, 32); cdA0 += __shfl_xor(cdA0, 32);
            ctA1 += __shfl_xor(ctA1, 32); cdA1 += __shfl_xor(cdA1, 32);
            ctA2 += __shfl_xor(ctA2, 32); cdA2 += __shfl_xor(cdA2, 32);
            ctA3 += __shfl_xor(ctA3, 32); cdA3 += __shfl_xor(cdA3, 32);
            if (quad == 0) {
                int cb = cbj * 128 + h * 64 + l16;
                atomicAdd(&tot[cb +  0], ctA0); atomicAdd(&dif[cb +  0], cdA0);
                atomicAdd(&tot[cb + 16], ctA1); atomicAdd(&dif[cb + 16], cdA1);
                atomicAdd(&tot[cb + 32], ctA2); atomicAdd(&dif[cb + 32], cdA2);
                atomicAdd(&tot[cb + 48], ctA3); atomicAdd(&dif[cb + 48], cdA3);
            }
        }
        __syncthreads();   // closes read window on tile[bufp]; drains next DMA

        if (h == 1) {      // advance to next tile
            cbi = nbi; cbj = nbj;
            if (++nbj == NT) { ++nbi; nbj = nbi; }
        }
    }
    FLUSH_ROWS(cur_bi);
}

// ---------------- fin ----------------
__global__ __launch_bounds__(1024) void fin_kernel(
    const float* __restrict__ tot, const float* __restrict__ dif,
    const float* __restrict__ sd, const float2* __restrict__ uc,
    float* __restrict__ out, int B)
{
    __shared__ float ssum[16], scnt[16];
    float sum = 0.0f, cnt = 0.0f;
    for (int i = threadIdx.x; i < B; i += 1024) {
        float u = uc[i].x;
        float P = tot[i];
        float Q = u * dif[i];
        // pos (excl. diag) = (P+Q)/2 - exp2(sd); invalid rows have P=Q=0 -> skipped
        float pos = 0.5f * (P + Q) - __builtin_amdgcn_exp2f(sd[i]);
        float neg = 0.5f * (P - Q);
        if (pos > 0.0f && neg > 0.0f) {
            sum += logf((pos + neg + 1e-8f) / pos);
            cnt += 1.0f;
        }
    }
    #pragma unroll
    for (int m = 32; m; m >>= 1) {
        sum += __shfl_xor(sum, m);
        cnt += __shfl_xor(cnt, m);
    }
    int wave = threadIdx.x >> 6, lane = threadIdx.x & 63;
    if (lane == 0) { ssum[wave] = sum; scnt[wave] = cnt; }
    __syncthreads();
    if (threadIdx.x == 0) {
        float S = 0.0f, C = 0.0f;
        #pragma unroll
        for (int w = 0; w < 16; ++w) { S += ssum[w]; C += scnt[w]; }
        out[0] = (C > 0.0f) ? S / fmaxf(C, 1.0f) : 0.0f;
    }
}

extern "C" void kernel_launch(void* const* d_in, const int* in_sizes, int n_in,
                              void* d_out, int out_size, void* d_ws, size_t ws_size,
                              hipStream_t stream) {
    const float* emb    = (const float*)d_in[0];
    const int*   labels = (const int*)d_in[1];
    const float* conf   = (const float*)d_in[2];
    float* out = (float*)d_out;
    int B = in_sizes[1];   // 8192

    char* ws = (char*)d_ws;
    size_t off = 0;
    short*  Eb  = (short*)(ws + off);  off += (size_t)B * DDIM * 2;
    float2* ucp = (float2*)(ws + off); off += (size_t)B * 8;
    float*  sd  = (float*)(ws + off);  off += (size_t)B * 4;
    float*  tot = (float*)(ws + off);  off += (size_t)B * 4;
    float*  dif = (float*)(ws + off);  off += (size_t)B * 4;

    prep_kernel<<<B / 4, 256, 0, stream>>>(emb, labels, conf, Eb, ucp, sd, tot, dif, B);

    int NT = B / 128;                      // 64 tiles per side
    int nblk = NT * (NT + 1) / 2 / CHUNK;  // 2080/2 = 1040 blocks -> ~4/CU
    sim_kernel<<<nblk, 256, 0, stream>>>(Eb, ucp, tot, dif, NT);

    fin_kernel<<<1, 1024, 0, stream>>>(tot, dif, sd, ucp, out, B);
}